// Round 1
// baseline (349.119 us; speedup 1.0000x reference)
//
#include <hip/hip_runtime.h>

#define NTOK 49
#define NPAD 64
#define CDIM 128
#define NWIN 64
#define SCALE 0.17677669529663687f

#define COMB_ELEMS (64*4*49*49)   // 614656 floats
#define PQKV_ELEMS (24*16*16*8)   // 49152 bf16
#define PPROJ_ELEMS (8*16*16*8)   // 16384 bf16

typedef __attribute__((ext_vector_type(8))) __bf16 bf16x8;
typedef __attribute__((ext_vector_type(4))) float f32x4;

__device__ __forceinline__ unsigned short f2bf(float f) {
  unsigned int u = __float_as_uint(f);
  u += 0x7fffu + ((u >> 16) & 1u);   // round-to-nearest-even
  return (unsigned short)(u >> 16);
}

// ---- prep: comb = mask + gathered rel-pos bias; pack weights to bf16 B-fragment layout ----
__global__ void prep_kernel(const float* __restrict__ mask,
                            const float* __restrict__ qkv_w,
                            const float* __restrict__ proj_w,
                            const float* __restrict__ bias_table,
                            const int* __restrict__ rel_index,
                            float* __restrict__ comb,
                            unsigned short* __restrict__ pqkv,
                            unsigned short* __restrict__ pproj) {
  int i = blockIdx.x * 256 + threadIdx.x;
  if (i < COMB_ELEMS) {
    int m = i % 49;
    int n = (i / 49) % 49;
    int h = (i / (49*49)) % 4;
    int w = i / (4*49*49);
    comb[i] = mask[(w*49 + n)*49 + m] + bias_table[rel_index[n*49 + m]*4 + h];
    return;
  }
  int j = i - COMB_ELEMS;
  if (j < PQKV_ELEMS) {
    // pqkv[ct][ko][n][jj] = Wqkv[ko*8+jj][ct*16+n]
    int jj = j & 7, nn = (j >> 3) & 15, ko = (j >> 7) & 15, ct = j >> 11;
    pqkv[j] = f2bf(qkv_w[(ko*8 + jj)*384 + ct*16 + nn]);
    return;
  }
  int p = j - PQKV_ELEMS;
  if (p < PPROJ_ELEMS) {
    int jj = p & 7, nn = (p >> 3) & 15, ko = (p >> 7) & 15, ct = p >> 11;
    pproj[p] = f2bf(proj_w[(ko*8 + jj)*128 + ct*16 + nn]);
  }
}

// ---- fused window attention: one block = one window (49 tokens), 4 waves = 4 heads ----
__global__ __launch_bounds__(256, 2) void win_attn_kernel(
    const float* __restrict__ x,
    const float* __restrict__ qkv_b,
    const float* __restrict__ proj_b,
    const float* __restrict__ comb,
    const unsigned short* __restrict__ pqkv,
    const unsigned short* __restrict__ pproj,
    float* __restrict__ out)
{
  // 64 KB total, aliased across stages:
  __shared__ alignas(16) unsigned short xo_lds[NPAD * CDIM];          // 16KB: x (A), then O (C/D)
  __shared__ alignas(16) unsigned short qkp_lds[2 * 4 * NPAD * 32];   // 32KB: q|k (A,B), then P (B,C)
  __shared__ alignas(16) unsigned short v_lds[4 * 32 * NPAD];         // 16KB: v^T (A,C)

  const int b    = blockIdx.x;
  const int tid  = threadIdx.x;
  const int wave = tid >> 6;
  const int lane = tid & 63;
  const int ln   = lane & 15;   // col-in-tile / A-row
  const int quad = lane >> 4;

  // zero pad rows 49..63 of x
  {
    unsigned int* zp = (unsigned int*)&xo_lds[NTOK * CDIM];
    for (int i = tid; i < (NPAD - NTOK) * CDIM / 2; i += 256) zp[i] = 0u;
  }
  // load x (49x128 fp32) -> bf16 row-major LDS
  {
    const float4* x4 = (const float4*)(x + (size_t)b * (NTOK * CDIM));
    for (int i = tid; i < NTOK * CDIM / 4; i += 256) {
      float4 f = x4[i];
      unsigned int lo = (unsigned int)f2bf(f.x) | ((unsigned int)f2bf(f.y) << 16);
      unsigned int hi = (unsigned int)f2bf(f.z) | ((unsigned int)f2bf(f.w) << 16);
      ((unsigned int*)xo_lds)[i*2]     = lo;
      ((unsigned int*)xo_lds)[i*2 + 1] = hi;
    }
  }
  __syncthreads();

  // ---------------- stage A: qkv = x @ Wqkv + qkv_b ----------------
  {
    bf16x8 afr[4][4];  // A-frags: [row-tile][k-step], reused across 6 col-tiles
    #pragma unroll
    for (int rt = 0; rt < 4; rt++)
      #pragma unroll
      for (int ks = 0; ks < 4; ks++)
        afr[rt][ks] = *(const bf16x8*)&xo_lds[(rt*16 + ln)*CDIM + ks*32 + quad*8];

    for (int ci = 0; ci < 6; ci++) {
      const int ct = wave * 6 + ci;              // col-tile 0..23 (cols of qkv)
      f32x4 acc[4];
      #pragma unroll
      for (int rt = 0; rt < 4; rt++) { f32x4 z = {0.f,0.f,0.f,0.f}; acc[rt] = z; }
      #pragma unroll
      for (int ks = 0; ks < 4; ks++) {
        bf16x8 bfr = *(const bf16x8*)&pqkv[((ct*16 + ks*4 + quad)*16 + ln)*8];
        #pragma unroll
        for (int rt = 0; rt < 4; rt++)
          acc[rt] = __builtin_amdgcn_mfma_f32_16x16x32_bf16(afr[rt][ks], bfr, acc[rt], 0, 0, 0);
      }
      const int c    = ct*16 + ln;
      const float bv = qkv_b[c];
      const int comp = c >> 7;          // 0=q 1=k 2=v (wave-uniform)
      const int h2   = (c >> 5) & 3;    // head (wave-uniform)
      const int dd   = c & 31;          // dim within head
      #pragma unroll
      for (int rt = 0; rt < 4; rt++) {
        #pragma unroll
        for (int r = 0; r < 4; r++) {
          const int nrow = rt*16 + quad*4 + r;   // C-layout row
          unsigned short val = f2bf(acc[rt][r] + bv);
          if (comp == 0)      qkp_lds[(h2*NPAD + nrow)*32 + dd] = val;              // q[h][n][d]
          else if (comp == 1) qkp_lds[4*NPAD*32 + (h2*NPAD + nrow)*32 + dd] = val;  // k[h][n][d]
          else                v_lds[(h2*32 + dd)*NPAD + nrow] = val;                // v^T[h][d][n]
        }
      }
    }
  }
  __syncthreads();

  // ---------------- stage B: S = scale*(q k^T) + comb; softmax ----------------
  const int h = wave;
  f32x4 sacc[4][4];   // [row-tile n][col-tile m]
  {
    const unsigned short* qh = &qkp_lds[h*NPAD*32];
    const unsigned short* kh = &qkp_lds[4*NPAD*32 + h*NPAD*32];
    bf16x8 qa[4], kb[4];
    #pragma unroll
    for (int rt = 0; rt < 4; rt++) qa[rt] = *(const bf16x8*)&qh[(rt*16 + ln)*32 + quad*8];
    #pragma unroll
    for (int ct = 0; ct < 4; ct++) kb[ct] = *(const bf16x8*)&kh[(ct*16 + ln)*32 + quad*8];
    #pragma unroll
    for (int rt = 0; rt < 4; rt++)
      #pragma unroll
      for (int ct = 0; ct < 4; ct++) {
        f32x4 z = {0.f,0.f,0.f,0.f};
        sacc[rt][ct] = __builtin_amdgcn_mfma_f32_16x16x32_bf16(qa[rt], kb[ct], z, 0, 0, 0);
      }
  }
  {
    const int w = b & (NWIN - 1);
    const float* cw = comb + (size_t)(w*4 + h)*NTOK*NTOK;
    #pragma unroll
    for (int rt = 0; rt < 4; rt++) {
      #pragma unroll
      for (int r = 0; r < 4; r++) {
        const int n  = rt*16 + quad*4 + r;
        const int nc = (n < NTOK) ? n : NTOK - 1;  // clamp pad rows (results unused)
        float sum = 0.f;
        #pragma unroll
        for (int ct = 0; ct < 4; ct++) {
          const int m = ct*16 + ln;
          float lgt = (m < NTOK) ? sacc[rt][ct][r]*SCALE + cw[nc*NTOK + m] : -1e30f;
          float e = __expf(lgt);     // logits tiny (~|0.5|); no max-sub needed; -100 mask -> 0
          sacc[rt][ct][r] = e;
          sum += e;
        }
        sum += __shfl_xor(sum, 1, 64);
        sum += __shfl_xor(sum, 2, 64);
        sum += __shfl_xor(sum, 4, 64);
        sum += __shfl_xor(sum, 8, 64);
        const float inv = 1.0f / sum;
        #pragma unroll
        for (int ct = 0; ct < 4; ct++) sacc[rt][ct][r] *= inv;
      }
    }
  }
  __syncthreads();   // everyone done reading q/k before P overwrites that region

  // P (bf16) into per-head 64x64 LDS region (C-layout -> row-major, for A-operand reads)
  unsigned short* ph = &qkp_lds[h * NPAD * NPAD];
  #pragma unroll
  for (int rt = 0; rt < 4; rt++)
    #pragma unroll
    for (int ct = 0; ct < 4; ct++)
      #pragma unroll
      for (int r = 0; r < 4; r++)
        ph[(rt*16 + quad*4 + r)*NPAD + ct*16 + ln] = f2bf(sacc[rt][ct][r]);

  // ---------------- stage C: O = P @ V ----------------
  f32x4 oacc[4][2];
  #pragma unroll
  for (int rt = 0; rt < 4; rt++)
    #pragma unroll
    for (int ct = 0; ct < 2; ct++) { f32x4 z = {0.f,0.f,0.f,0.f}; oacc[rt][ct] = z; }
  #pragma unroll
  for (int ks = 0; ks < 2; ks++) {
    bf16x8 vb[2];
    #pragma unroll
    for (int ct = 0; ct < 2; ct++)
      vb[ct] = *(const bf16x8*)&v_lds[(h*32 + ct*16 + ln)*NPAD + ks*32 + quad*8];
    #pragma unroll
    for (int rt = 0; rt < 4; rt++) {
      bf16x8 pa = *(const bf16x8*)&ph[(rt*16 + ln)*NPAD + ks*32 + quad*8];
      #pragma unroll
      for (int ct = 0; ct < 2; ct++)
        oacc[rt][ct] = __builtin_amdgcn_mfma_f32_16x16x32_bf16(pa, vb[ct], oacc[rt][ct], 0, 0, 0);
    }
  }
  // O (bf16) -> xo_lds[n][h*32+d]  (x region is dead)
  #pragma unroll
  for (int rt = 0; rt < 4; rt++)
    #pragma unroll
    for (int ct = 0; ct < 2; ct++)
      #pragma unroll
      for (int r = 0; r < 4; r++) {
        const int row = rt*16 + quad*4 + r;
        const int col = h*32 + ct*16 + ln;
        xo_lds[row*CDIM + col] = f2bf(oacc[rt][ct][r]);
      }
  __syncthreads();

  // ---------------- stage D: out = O @ Wproj + proj_b ----------------
  {
    bf16x8 oa[4][4];
    #pragma unroll
    for (int rt = 0; rt < 4; rt++)
      #pragma unroll
      for (int ks = 0; ks < 4; ks++)
        oa[rt][ks] = *(const bf16x8*)&xo_lds[(rt*16 + ln)*CDIM + ks*32 + quad*8];
    float* ob = out + (size_t)b * (NTOK * CDIM);
    #pragma unroll
    for (int ci = 0; ci < 2; ci++) {
      const int ct = wave*2 + ci;   // col-tile 0..7
      f32x4 pacc[4];
      #pragma unroll
      for (int rt = 0; rt < 4; rt++) { f32x4 z = {0.f,0.f,0.f,0.f}; pacc[rt] = z; }
      #pragma unroll
      for (int ks = 0; ks < 4; ks++) {
        bf16x8 bfr = *(const bf16x8*)&pproj[((ct*16 + ks*4 + quad)*16 + ln)*8];
        #pragma unroll
        for (int rt = 0; rt < 4; rt++)
          pacc[rt] = __builtin_amdgcn_mfma_f32_16x16x32_bf16(oa[rt][ks], bfr, pacc[rt], 0, 0, 0);
      }
      const int c = ct*16 + ln;
      const float pb = proj_b[c];
      #pragma unroll
      for (int rt = 0; rt < 4; rt++)
        #pragma unroll
        for (int r = 0; r < 4; r++) {
          const int n = rt*16 + quad*4 + r;
          if (n < NTOK) ob[n*CDIM + c] = pacc[rt][r] + pb;
        }
    }
  }
}

extern "C" void kernel_launch(void* const* d_in, const int* in_sizes, int n_in,
                              void* d_out, int out_size, void* d_ws, size_t ws_size,
                              hipStream_t stream) {
  const float* x          = (const float*)d_in[0];
  const float* mask       = (const float*)d_in[1];
  const float* qkv_w      = (const float*)d_in[2];
  const float* qkv_b      = (const float*)d_in[3];
  const float* proj_w     = (const float*)d_in[4];
  const float* proj_b     = (const float*)d_in[5];
  const float* bias_table = (const float*)d_in[6];
  const int*   rel_index  = (const int*)d_in[7];
  float* out = (float*)d_out;

  char* ws = (char*)d_ws;
  float* comb           = (float*)ws;
  unsigned short* pqkv  = (unsigned short*)(ws + (size_t)COMB_ELEMS*4);
  unsigned short* pproj = (unsigned short*)(ws + (size_t)COMB_ELEMS*4 + (size_t)PQKV_ELEMS*2);

  const int total = COMB_ELEMS + PQKV_ELEMS + PPROJ_ELEMS;
  prep_kernel<<<(total + 255)/256, 256, 0, stream>>>(
      mask, qkv_w, proj_w, bias_table, rel_index, comb, pqkv, pproj);
  win_attn_kernel<<<4096, 256, 0, stream>>>(
      x, qkv_b, proj_b, comb, pqkv, pproj, out);
}

// Round 2
// 294.058 us; speedup vs baseline: 1.1872x; 1.1872x over previous
//
#include <hip/hip_runtime.h>

#define NTOK 49
#define CDIM 128
#define NWIN 64
#define SCALE 0.17677669529663687f

#define COMB_ELEMS (64*4*49*49)   // 614656 floats
#define PQKV_ELEMS (24*16*16*8)   // 49152 bf16
#define PPROJ_ELEMS (8*16*16*8)   // 16384 bf16

// LDS layout (units: shorts). Per-wave head ownership.
//   qk_h at h*QK_H : q rows[0,56) stride 40, k at +KOFF. P_h aliases qk_h (rows<56, stride 72).
//   v_h  at VOFF + h*V_H : v^T rows=d[0,32) stride 72 (cols = token).
//   O aliases [VOFF, +56*136): rows<56 stride 136, cols 0..127.
// Strides chosen so C-frag scatter writes spread quads across banks:
//   40 shorts: quad step = 4*40 sh = 80 dw = 16 mod 32 (2-way, free); rows 16B-aligned.
//   72 shorts: lane step 36 dw = 4 mod 32 -> 32 distinct banks over (ln,quad); 16B-aligned.
//   136 shorts: quad step 4*136 sh = 272 dw = 16 mod 32 (2-way, free); 16B-aligned.
#define QK_STRIDE 40
#define QK_ROWS 56
#define KOFF (QK_ROWS*QK_STRIDE)      // 2240
#define QK_H (2*KOFF)                 // 4480
#define P_STRIDE 72
#define V_STRIDE 72
#define VOFF (4*QK_H)                 // 17920
#define V_H (32*V_STRIDE)             // 2304
#define O_STRIDE 136
#define LDS_SHORTS (VOFF + 4*V_H)     // 27136 shorts = 54272 B = 53 KB -> 3 blocks/CU

typedef __attribute__((ext_vector_type(8))) __bf16 bf16x8;
typedef __attribute__((ext_vector_type(4))) float f32x4;

__device__ __forceinline__ unsigned int f2bf(float f) {
  unsigned int u = __float_as_uint(f);
  u += 0x7fffu + ((u >> 16) & 1u);   // round-to-nearest-even
  return u >> 16;
}

__device__ __forceinline__ bf16x8 pack8(float4 a, float4 b) {
  union { bf16x8 v; unsigned int u[4]; } r;
  r.u[0] = f2bf(a.x) | (f2bf(a.y) << 16);
  r.u[1] = f2bf(a.z) | (f2bf(a.w) << 16);
  r.u[2] = f2bf(b.x) | (f2bf(b.y) << 16);
  r.u[3] = f2bf(b.z) | (f2bf(b.w) << 16);
  return r.v;
}

// ---- prep: comb = mask + gathered rel-pos bias; pack weights to bf16 B-fragment layout ----
__global__ void prep_kernel(const float* __restrict__ mask,
                            const float* __restrict__ qkv_w,
                            const float* __restrict__ proj_w,
                            const float* __restrict__ bias_table,
                            const int* __restrict__ rel_index,
                            float* __restrict__ comb,
                            unsigned short* __restrict__ pqkv,
                            unsigned short* __restrict__ pproj) {
  int i = blockIdx.x * 256 + threadIdx.x;
  if (i < COMB_ELEMS) {
    int m = i % 49;
    int n = (i / 49) % 49;
    int h = (i / (49*49)) % 4;
    int w = i / (4*49*49);
    comb[i] = mask[(w*49 + n)*49 + m] + bias_table[rel_index[n*49 + m]*4 + h];
    return;
  }
  int j = i - COMB_ELEMS;
  if (j < PQKV_ELEMS) {
    // pqkv[ct][ko][n][jj] = Wqkv[ko*8+jj][ct*16+n]
    int jj = j & 7, nn = (j >> 3) & 15, ko = (j >> 7) & 15, ct = j >> 11;
    pqkv[j] = (unsigned short)f2bf(qkv_w[(ko*8 + jj)*384 + ct*16 + nn]);
    return;
  }
  int p = j - PQKV_ELEMS;
  if (p < PPROJ_ELEMS) {
    int jj = p & 7, nn = (p >> 3) & 15, ko = (p >> 7) & 15, ct = p >> 11;
    pproj[p] = (unsigned short)f2bf(proj_w[(ko*8 + jj)*128 + ct*16 + nn]);
  }
}

// ---- fused window attention: 1 block = 1 window, wave h owns head h end-to-end ----
__global__ __launch_bounds__(256, 3) void win_attn_kernel(
    const float* __restrict__ x,
    const float* __restrict__ qkv_b,
    const float* __restrict__ proj_b,
    const float* __restrict__ comb,
    const unsigned short* __restrict__ pqkv,
    const unsigned short* __restrict__ pproj,
    float* __restrict__ out)
{
  __shared__ alignas(16) unsigned short lds[LDS_SHORTS];

  const int b    = blockIdx.x;
  const int tid  = threadIdx.x;
  const int wave = tid >> 6;
  const int lane = tid & 63;
  const int ln   = lane & 15;
  const int quad = lane >> 4;
  const int h    = wave;

  unsigned short* qk = lds + h * QK_H;
  unsigned short* vh = lds + VOFF + h * V_H;

  // zero v^T cols 56..63 (read by stage C as B-frag tail, never written; avoid NaN garbage)
  {
    const int d0 = lane >> 1;              // 0..31
    const int n0 = 56 + (lane & 1) * 4;    // 56 or 60
    *(unsigned long long*)&vh[d0 * V_STRIDE + n0] = 0ull;
  }

  // ---- x A-fragments straight from global (rows >= 49 -> zero) ----
  bf16x8 afr[4][4];
  {
    const float* xb = x + (size_t)b * (NTOK * CDIM);
    #pragma unroll
    for (int rt = 0; rt < 4; rt++) {
      const int row = rt*16 + ln;
      #pragma unroll
      for (int ks = 0; ks < 4; ks++) {
        if (row < NTOK) {
          const float* p = xb + row*CDIM + ks*32 + quad*8;
          afr[rt][ks] = pack8(*(const float4*)p, *(const float4*)(p + 4));
        } else {
          union { bf16x8 v; unsigned int u[4]; } z;
          z.u[0] = z.u[1] = z.u[2] = z.u[3] = 0u;
          afr[rt][ks] = z.v;
        }
      }
    }
  }

  // ---------------- stage A: q/k/v for head h only (tiles 2h,2h+1 / 8+.. / 16+..) ----------------
  #pragma unroll
  for (int comp = 0; comp < 3; comp++) {
    #pragma unroll
    for (int ci = 0; ci < 2; ci++) {
      const int ct = comp*8 + h*2 + ci;
      f32x4 acc[4];
      #pragma unroll
      for (int rt = 0; rt < 4; rt++) { f32x4 z = {0.f,0.f,0.f,0.f}; acc[rt] = z; }
      #pragma unroll
      for (int ks = 0; ks < 4; ks++) {
        bf16x8 bfr = *(const bf16x8*)&pqkv[((ct*16 + ks*4 + quad)*16 + ln)*8];
        #pragma unroll
        for (int rt = 0; rt < 4; rt++)
          acc[rt] = __builtin_amdgcn_mfma_f32_16x16x32_bf16(afr[rt][ks], bfr, acc[rt], 0, 0, 0);
      }
      const float bv = qkv_b[ct*16 + ln];
      const int dd = ci*16 + ln;   // d within head
      #pragma unroll
      for (int rt = 0; rt < 4; rt++)
        #pragma unroll
        for (int r = 0; r < 4; r++) {
          const int nrow = rt*16 + quad*4 + r;
          if (nrow < QK_ROWS) {
            unsigned short val = (unsigned short)f2bf(acc[rt][r] + bv);
            if (comp == 0)      qk[nrow*QK_STRIDE + dd] = val;
            else if (comp == 1) qk[KOFF + nrow*QK_STRIDE + dd] = val;
            else                vh[dd*V_STRIDE + nrow] = val;
          }
        }
    }
  }

  // ---- comb prefetch into registers (independent of LDS; hidden behind QK^T) ----
  float cmb[4][4][4];
  {
    const float* cw = comb + (size_t)((b & (NWIN-1))*4 + h) * (NTOK*NTOK);
    #pragma unroll
    for (int rt = 0; rt < 4; rt++)
      #pragma unroll
      for (int r = 0; r < 4; r++) {
        const int n  = rt*16 + quad*4 + r;
        const int nc = (n < NTOK) ? n : NTOK - 1;
        #pragma unroll
        for (int ct = 0; ct < 4; ct++) {
          const int m = ct*16 + ln;
          cmb[rt][r][ct] = (m < NTOK) ? cw[nc*NTOK + m] : 0.0f;
        }
      }
  }

  // ---------------- stage B: S = q k^T (per-wave, no barrier needed) ----------------
  f32x4 sacc[4][4];
  {
    bf16x8 qa[4], kb[4];
    #pragma unroll
    for (int rt = 0; rt < 4; rt++) {
      int rr = rt*16 + ln; if (rr > QK_ROWS-1) rr = QK_ROWS-1;
      qa[rt] = *(const bf16x8*)&qk[rr*QK_STRIDE + quad*8];
    }
    #pragma unroll
    for (int ct = 0; ct < 4; ct++) {
      int rr = ct*16 + ln; if (rr > QK_ROWS-1) rr = QK_ROWS-1;
      kb[ct] = *(const bf16x8*)&qk[KOFF + rr*QK_STRIDE + quad*8];
    }
    #pragma unroll
    for (int rt = 0; rt < 4; rt++)
      #pragma unroll
      for (int ct = 0; ct < 4; ct++) {
        f32x4 z = {0.f,0.f,0.f,0.f};
        sacc[rt][ct] = __builtin_amdgcn_mfma_f32_16x16x32_bf16(qa[rt], kb[ct], z, 0, 0, 0);
      }
  }

  // softmax: rows n = rt*16+quad*4+r, cols m = ct*16+ln; reduce over ln with shfl
  #pragma unroll
  for (int rt = 0; rt < 4; rt++)
    #pragma unroll
    for (int r = 0; r < 4; r++) {
      float sum = 0.f;
      #pragma unroll
      for (int ct = 0; ct < 4; ct++) {
        const int m = ct*16 + ln;
        float lgt = (m < NTOK) ? sacc[rt][ct][r]*SCALE + cmb[rt][r][ct] : -1e30f;
        float e = __expf(lgt);   // logits tiny; -100 mask underflows to 0
        sacc[rt][ct][r] = e;
        sum += e;
      }
      sum += __shfl_xor(sum, 1, 64);
      sum += __shfl_xor(sum, 2, 64);
      sum += __shfl_xor(sum, 4, 64);
      sum += __shfl_xor(sum, 8, 64);
      const float inv = 1.0f / sum;
      #pragma unroll
      for (int ct = 0; ct < 4; ct++) sacc[rt][ct][r] *= inv;
    }

  // P -> LDS (aliases THIS wave's q/k region; per-wave DS ops are in-order, no barrier)
  unsigned short* ph = qk;
  #pragma unroll
  for (int rt = 0; rt < 4; rt++)
    #pragma unroll
    for (int ct = 0; ct < 4; ct++)
      #pragma unroll
      for (int r = 0; r < 4; r++) {
        const int nrow = rt*16 + quad*4 + r;
        if (nrow < QK_ROWS)
          ph[nrow*P_STRIDE + ct*16 + ln] = (unsigned short)f2bf(sacc[rt][ct][r]);
      }

  // ---------------- stage C: O_h = P_h @ V_h (per-wave) ----------------
  f32x4 oacc[4][2];
  #pragma unroll
  for (int rt = 0; rt < 4; rt++)
    #pragma unroll
    for (int ct = 0; ct < 2; ct++) { f32x4 z = {0.f,0.f,0.f,0.f}; oacc[rt][ct] = z; }
  #pragma unroll
  for (int ks = 0; ks < 2; ks++) {
    bf16x8 vb[2];
    #pragma unroll
    for (int ct = 0; ct < 2; ct++)
      vb[ct] = *(const bf16x8*)&vh[(ct*16 + ln)*V_STRIDE + ks*32 + quad*8];
    #pragma unroll
    for (int rt = 0; rt < 4; rt++) {
      int rr = rt*16 + ln; if (rr > QK_ROWS-1) rr = QK_ROWS-1;
      bf16x8 pa = *(const bf16x8*)&ph[rr*P_STRIDE + ks*32 + quad*8];
      #pragma unroll
      for (int ct = 0; ct < 2; ct++)
        oacc[rt][ct] = __builtin_amdgcn_mfma_f32_16x16x32_bf16(pa, vb[ct], oacc[rt][ct], 0, 0, 0);
    }
  }

  __syncthreads();   // all waves done reading v before O overlays the v region
  unsigned short* oo = lds + VOFF;
  #pragma unroll
  for (int rt = 0; rt < 4; rt++)
    #pragma unroll
    for (int ct = 0; ct < 2; ct++)
      #pragma unroll
      for (int r = 0; r < 4; r++) {
        const int nrow = rt*16 + quad*4 + r;
        if (nrow < QK_ROWS)
          oo[nrow*O_STRIDE + h*32 + ct*16 + ln] = (unsigned short)f2bf(oacc[rt][ct][r]);
      }
  __syncthreads();   // O complete before cross-head reads

  // ---------------- stage D: out = O @ Wproj + proj_b ----------------
  {
    bf16x8 oa[4][4];
    #pragma unroll
    for (int rt = 0; rt < 4; rt++) {
      int rr = rt*16 + ln; if (rr > QK_ROWS-1) rr = QK_ROWS-1;
      #pragma unroll
      for (int ks = 0; ks < 4; ks++)
        oa[rt][ks] = *(const bf16x8*)&oo[rr*O_STRIDE + ks*32 + quad*8];
    }
    float* ob = out + (size_t)b * (NTOK * CDIM);
    #pragma unroll
    for (int ci = 0; ci < 2; ci++) {
      const int ct = h*2 + ci;
      f32x4 pacc[4];
      #pragma unroll
      for (int rt = 0; rt < 4; rt++) { f32x4 z = {0.f,0.f,0.f,0.f}; pacc[rt] = z; }
      #pragma unroll
      for (int ks = 0; ks < 4; ks++) {
        bf16x8 bfr = *(const bf16x8*)&pproj[((ct*16 + ks*4 + quad)*16 + ln)*8];
        #pragma unroll
        for (int rt = 0; rt < 4; rt++)
          pacc[rt] = __builtin_amdgcn_mfma_f32_16x16x32_bf16(oa[rt][ks], bfr, pacc[rt], 0, 0, 0);
      }
      const int c = ct*16 + ln;
      const float pb = proj_b[c];
      #pragma unroll
      for (int rt = 0; rt < 4; rt++)
        #pragma unroll
        for (int r = 0; r < 4; r++) {
          const int n = rt*16 + quad*4 + r;
          if (n < NTOK) ob[n*CDIM + c] = pacc[rt][r] + pb;
        }
    }
  }
}

extern "C" void kernel_launch(void* const* d_in, const int* in_sizes, int n_in,
                              void* d_out, int out_size, void* d_ws, size_t ws_size,
                              hipStream_t stream) {
  const float* x          = (const float*)d_in[0];
  const float* mask       = (const float*)d_in[1];
  const float* qkv_w      = (const float*)d_in[2];
  const float* qkv_b      = (const float*)d_in[3];
  const float* proj_w     = (const float*)d_in[4];
  const float* proj_b     = (const float*)d_in[5];
  const float* bias_table = (const float*)d_in[6];
  const int*   rel_index  = (const int*)d_in[7];
  float* out = (float*)d_out;

  char* ws = (char*)d_ws;
  float* comb           = (float*)ws;
  unsigned short* pqkv  = (unsigned short*)(ws + (size_t)COMB_ELEMS*4);
  unsigned short* pproj = (unsigned short*)(ws + (size_t)COMB_ELEMS*4 + (size_t)PQKV_ELEMS*2);

  const int total = COMB_ELEMS + PQKV_ELEMS + PPROJ_ELEMS;
  prep_kernel<<<(total + 255)/256, 256, 0, stream>>>(
      mask, qkv_w, proj_w, bias_table, rel_index, comb, pqkv, pproj);
  win_attn_kernel<<<4096, 256, 0, stream>>>(
      x, qkv_b, proj_b, comb, pqkv, pproj, out);
}

// Round 3
// 272.547 us; speedup vs baseline: 1.2809x; 1.0789x over previous
//
#include <hip/hip_runtime.h>
#include <hip/hip_bf16.h>

#define NTOK 49
#define CDIM 128
#define SCALE 0.17677669529663687f

// packed table sizes (elements)
#define MASKT_ELEMS (64*64*16*4)      // 262144 f32  [w][m][ln][ct] = mask + pad (-1e30 rows m>=49)
#define RPBT_ELEMS  (4*64*16*4)       // 16384 f32   [h][m][ln][ct]
#define PWQK_ELEMS  (4*4*4*4*16*8)    // 32768 bf16  [h][rt][ks][quad][ln][j]  (A-frags of Wq/Wk^T)
#define PV_ELEMS    (8*4*4*16*8)      // 16384 bf16  [c2][ks][quad][ln][j]     (B-frags of Wv)
#define PWP_ELEMS   (8*4*4*16*8)      // 16384 bf16  [rt][ks][quad][ln][j]     (A-frags of Wproj^T)

// LDS layout (units: shorts), per head region HSZ:
//   q[n 0..63][d stride QS=36] @0 ; k @KOFFS ; P[n][m stride PS=68] aliases q+k
//   v^T[d 0..31][m stride VS=68] @VOFFS ; O-slice[n<56][c-in-head stride OS=36] aliases v
// All row strides are mult-of-4 shorts (8B-aligned b64 ops) with stride/2 ≡ 2 mod 4
// -> 16-lane access spreads over 16 distinct bank(-pair)s: 2-way aliasing = free (m136).
#define QS 36
#define PS 68
#define VS 68
#define OS 36
#define KOFFS (64*QS)          // 2304
#define VOFFS (2*KOFFS)        // 4608
#define HSZ   (VOFFS + 32*VS)  // 6784
#define LDS_SH (4*HSZ + 128)   // 27264 shorts = 54528 B -> 3 blocks/CU (163584 <= 163840)

typedef __attribute__((ext_vector_type(8))) __bf16 bf16x8;
typedef __attribute__((ext_vector_type(4))) float f32x4;

__device__ __forceinline__ unsigned short f2bf(float f) {
  unsigned int u = __float_as_uint(f);
  u += 0x7fffu + ((u >> 16) & 1u);   // RTNE
  return (unsigned short)(u >> 16);
}

__device__ __forceinline__ unsigned int pk2(float a, float b) {
  union { __hip_bfloat162 h2; unsigned int u; } r;
  r.h2 = __float22bfloat162_rn(make_float2(a, b));
  return r.u;
}
__device__ __forceinline__ unsigned long long pk4(float a, float b, float c, float d) {
  return (unsigned long long)pk2(a, b) | ((unsigned long long)pk2(c, d) << 32);
}
__device__ __forceinline__ bf16x8 pack8(float4 a, float4 b) {
  union { bf16x8 v; unsigned int u[4]; } r;
  r.u[0] = pk2(a.x, a.y); r.u[1] = pk2(a.z, a.w);
  r.u[2] = pk2(b.x, b.y); r.u[3] = pk2(b.z, b.w);
  return r.v;
}
// two ds_read_b64 (rows are 8B- but not 16B-aligned)
__device__ __forceinline__ bf16x8 ld8(const unsigned short* p) {
  union { bf16x8 v; unsigned long long q[2]; } r;
  r.q[0] = *(const unsigned long long*)(p);
  r.q[1] = *(const unsigned long long*)(p + 4);
  return r.v;
}

// ---- prep: swizzled mask/rpb tables + weight fragments ----
__global__ void prep_kernel(const float* __restrict__ mask,
                            const float* __restrict__ qkv_w,
                            const float* __restrict__ proj_w,
                            const float* __restrict__ bias_table,
                            const int* __restrict__ rel_index,
                            float* __restrict__ mask_t,
                            float* __restrict__ rpb_t,
                            unsigned short* __restrict__ pwqk,
                            unsigned short* __restrict__ pv,
                            unsigned short* __restrict__ pwp) {
  int i = blockIdx.x * 256 + threadIdx.x;
  if (i < MASKT_ELEMS) {
    int ct = i & 3, ln = (i >> 2) & 15, m = (i >> 6) & 63, w = i >> 12;
    int n = ct * 16 + ln;
    float v;
    if (m < NTOK) v = (n < NTOK) ? mask[(w * NTOK + n) * NTOK + m] : 0.0f;
    else          v = -1e30f;     // rows m>=49: exp -> 0
    mask_t[i] = v;
    return;
  }
  i -= MASKT_ELEMS;
  if (i < RPBT_ELEMS) {
    int ct = i & 3, ln = (i >> 2) & 15, m = (i >> 6) & 63, h = i >> 12;
    int n = ct * 16 + ln;
    rpb_t[i] = (m < NTOK && n < NTOK) ? bias_table[rel_index[n * NTOK + m] * 4 + h] : 0.0f;
    return;
  }
  i -= RPBT_ELEMS;
  if (i < PWQK_ELEMS) {
    int j = i & 7, ln = (i >> 3) & 15, quad = (i >> 7) & 3, ks = (i >> 9) & 3,
        rt = (i >> 11) & 3, h = (i >> 13) & 3;
    int kk  = ks * 32 + quad * 8 + j;
    int col = (rt < 2) ? (h * 32 + rt * 16 + ln) : (128 + h * 32 + (rt - 2) * 16 + ln);
    pwqk[i] = f2bf(qkv_w[kk * 384 + col]);
    return;
  }
  i -= PWQK_ELEMS;
  if (i < PV_ELEMS) {
    int j = i & 7, ln = (i >> 3) & 15, quad = (i >> 7) & 3, ks = (i >> 9) & 3, c2 = (i >> 11) & 7;
    pv[i] = f2bf(qkv_w[(ks * 32 + quad * 8 + j) * 384 + 256 + c2 * 16 + ln]);
    return;
  }
  i -= PV_ELEMS;
  if (i < PWP_ELEMS) {
    int j = i & 7, ln = (i >> 3) & 15, quad = (i >> 7) & 3, ks = (i >> 9) & 3, rt = (i >> 11) & 7;
    pwp[i] = f2bf(proj_w[(ks * 32 + quad * 8 + j) * 128 + rt * 16 + ln]);
  }
}

// ---- fused window attention: 1 block = 1 window, wave h owns head h; ONE barrier total ----
__global__ __launch_bounds__(256, 3) void win_attn_kernel(
    const float* __restrict__ x,
    const float* __restrict__ qkv_b,
    const float* __restrict__ proj_b,
    const float* __restrict__ mask_t,
    const float* __restrict__ rpb_t,
    const unsigned short* __restrict__ pwqk,
    const unsigned short* __restrict__ pv,
    const unsigned short* __restrict__ pwp,
    float* __restrict__ out)
{
  __shared__ alignas(16) unsigned short lds[LDS_SH];

  const int b    = blockIdx.x;
  const int tid  = threadIdx.x;
  const int h    = tid >> 6;
  const int lane = tid & 63;
  const int ln   = lane & 15;
  const int quad = lane >> 4;

  unsigned short* hb = lds + h * HSZ;

  // ---- x fragments from global: serve as A (rows=tokens) for v-GEMM and B (cols=tokens) for q/k ----
  bf16x8 afr[4][4];
  {
    const float* xb = x + (size_t)b * (NTOK * CDIM);
    #pragma unroll
    for (int rt = 0; rt < 4; rt++) {
      const int row = rt * 16 + ln;
      #pragma unroll
      for (int ks = 0; ks < 4; ks++) {
        if (row < NTOK) {
          const float* p = xb + row * CDIM + ks * 32 + quad * 8;
          afr[rt][ks] = pack8(*(const float4*)p, *(const float4*)(p + 4));
        } else {
          union { bf16x8 v; unsigned int u[4]; } z;
          z.u[0] = z.u[1] = z.u[2] = z.u[3] = 0u;
          afr[rt][ks] = z.v;   // pad tokens -> 0; downstream q/k/v pad entries = bias (finite)
        }
      }
    }
  }

  // ---------------- stage A-v: v = x @ Wv (normal orient; C rows=tokens) ----------------
  #pragma unroll
  for (int ci = 0; ci < 2; ci++) {
    bf16x8 bvf[4];
    #pragma unroll
    for (int ks = 0; ks < 4; ks++)
      bvf[ks] = *(const bf16x8*)&pv[((((h*2 + ci)*4 + ks)*4 + quad)*16 + ln)*8];
    const float bvb = qkv_b[256 + (h*2 + ci)*16 + ln];
    f32x4 acc[4];
    #pragma unroll
    for (int rt = 0; rt < 4; rt++) { f32x4 bi = {bvb, bvb, bvb, bvb}; acc[rt] = bi; }
    #pragma unroll
    for (int ks = 0; ks < 4; ks++)
      #pragma unroll
      for (int rt = 0; rt < 4; rt++)
        acc[rt] = __builtin_amdgcn_mfma_f32_16x16x32_bf16(afr[rt][ks], bvf[ks], acc[rt], 0, 0, 0);
    // C: row=token m (quad*4+r), col=d (ln)  ->  v^T[d][m], m r-consecutive -> b64
    #pragma unroll
    for (int rt = 0; rt < 4; rt++)
      *(unsigned long long*)&hb[VOFFS + (ci*16 + ln)*VS + rt*16 + quad*4] =
          pk4(acc[rt][0], acc[rt][1], acc[rt][2], acc[rt][3]);
  }

  // ---------------- stage A-qk: qkv^T = W^T @ x^T (C rows=features) ----------------
  #pragma unroll
  for (int rt = 0; rt < 4; rt++) {
    bf16x8 awf[4];
    #pragma unroll
    for (int ks = 0; ks < 4; ks++)
      awf[ks] = *(const bf16x8*)&pwqk[((((h*4 + rt)*4 + ks)*4 + quad)*16 + ln)*8];
    const int fb = (rt < 2) ? (h*32 + rt*16 + quad*4) : (128 + h*32 + (rt - 2)*16 + quad*4);
    const float4 qb4 = *(const float4*)&qkv_b[fb];
    f32x4 acc2[4];
    #pragma unroll
    for (int ct = 0; ct < 4; ct++) { f32x4 bi = {qb4.x, qb4.y, qb4.z, qb4.w}; acc2[ct] = bi; }
    #pragma unroll
    for (int ks = 0; ks < 4; ks++)
      #pragma unroll
      for (int ct = 0; ct < 4; ct++)
        acc2[ct] = __builtin_amdgcn_mfma_f32_16x16x32_bf16(awf[ks], afr[ct][ks], acc2[ct], 0, 0, 0);
    // C: row=feature (quad*4+r), col=token n (ln) -> q[n][d] / k[m][d], d r-consecutive -> b64
    const int base = (rt < 2) ? 0 : KOFFS;
    const int d0   = (rt < 2) ? (rt*16 + quad*4) : ((rt - 2)*16 + quad*4);
    const float sc = (rt < 2) ? SCALE : 1.0f;   // fold softmax scale into q
    #pragma unroll
    for (int ct = 0; ct < 4; ct++)
      *(unsigned long long*)&hb[base + (ct*16 + ln)*QS + d0] =
          pk4(acc2[ct][0]*sc, acc2[ct][1]*sc, acc2[ct][2]*sc, acc2[ct][3]*sc);
  }

  // ---------------- stage B: S^T = k · q^T, acc-initialized with mask+rpb ----------------
  f32x4 sacc[4][4];   // [rt: m-tile][ct: n-tile]
  {
    const float* mw = mask_t + (size_t)(b & 63) * (64*64);
    const float* rw = rpb_t  + (size_t)h * (64*64);
    #pragma unroll
    for (int rt = 0; rt < 4; rt++)
      #pragma unroll
      for (int r = 0; r < 4; r++) {
        const int m = rt*16 + quad*4 + r;
        const float4 fm = *(const float4*)(mw + (m*16 + ln)*4);
        const float4 fr = *(const float4*)(rw + (m*16 + ln)*4);
        sacc[rt][0][r] = fm.x + fr.x;
        sacc[rt][1][r] = fm.y + fr.y;
        sacc[rt][2][r] = fm.z + fr.z;
        sacc[rt][3][r] = fm.w + fr.w;
      }
    bf16x8 ka[4], qb2[4];
    #pragma unroll
    for (int rt = 0; rt < 4; rt++) ka[rt]  = ld8(&hb[KOFFS + (rt*16 + ln)*QS + quad*8]);
    #pragma unroll
    for (int ct = 0; ct < 4; ct++) qb2[ct] = ld8(&hb[(ct*16 + ln)*QS + quad*8]);
    #pragma unroll
    for (int rt = 0; rt < 4; rt++)
      #pragma unroll
      for (int ct = 0; ct < 4; ct++)
        sacc[rt][ct] = __builtin_amdgcn_mfma_f32_16x16x32_bf16(ka[rt], qb2[ct], sacc[rt][ct], 0, 0, 0);
  }

  // ---------------- softmax over m (rows): lane-partial + 2 shuffles ----------------
  float inv[4];
  #pragma unroll
  for (int ct = 0; ct < 4; ct++) {
    float s = 0.0f;
    #pragma unroll
    for (int rt = 0; rt < 4; rt++)
      #pragma unroll
      for (int r = 0; r < 4; r++) {
        const float e = __expf(sacc[rt][ct][r]);   // m>=49 rows: -1e30 -> 0
        sacc[rt][ct][r] = e;
        s += e;
      }
    s += __shfl_xor(s, 16, 64);
    s += __shfl_xor(s, 32, 64);
    inv[ct] = 1.0f / s;
  }
  // P[n][m] (m r-consecutive -> b64); aliases own q/k region (per-wave DS is in-order)
  #pragma unroll
  for (int rt = 0; rt < 4; rt++)
    #pragma unroll
    for (int ct = 0; ct < 4; ct++)
      *(unsigned long long*)&hb[(ct*16 + ln)*PS + rt*16 + quad*4] =
          pk4(sacc[rt][0 ? 0 : ct][0]*inv[ct], sacc[rt][ct][1]*inv[ct],
              sacc[rt][ct][2]*inv[ct], sacc[rt][ct][3]*inv[ct]);

  // ---------------- stage C: O^T = v^T · P^T (C rows=d, cols=n) ----------------
  {
    bf16x8 va[2][2], pb[4][2];
    #pragma unroll
    for (int rt = 0; rt < 2; rt++)
      #pragma unroll
      for (int ks = 0; ks < 2; ks++)
        va[rt][ks] = ld8(&hb[VOFFS + (rt*16 + ln)*VS + ks*32 + quad*8]);
    #pragma unroll
    for (int ct = 0; ct < 4; ct++)
      #pragma unroll
      for (int ks = 0; ks < 2; ks++)
        pb[ct][ks] = ld8(&hb[(ct*16 + ln)*PS + ks*32 + quad*8]);
    f32x4 oacc[2][4];
    #pragma unroll
    for (int rt = 0; rt < 2; rt++)
      #pragma unroll
      for (int ct = 0; ct < 4; ct++) { f32x4 z = {0.f, 0.f, 0.f, 0.f}; oacc[rt][ct] = z; }
    #pragma unroll
    for (int ks = 0; ks < 2; ks++)
      #pragma unroll
      for (int rt = 0; rt < 2; rt++)
        #pragma unroll
        for (int ct = 0; ct < 4; ct++)
          oacc[rt][ct] = __builtin_amdgcn_mfma_f32_16x16x32_bf16(va[rt][ks], pb[ct][ks], oacc[rt][ct], 0, 0, 0);
    // O[n][c-in-head] (c r-consecutive -> b64) into own head's O slice (aliases own v; no barrier needed)
    #pragma unroll
    for (int rt = 0; rt < 2; rt++)
      #pragma unroll
      for (int ct = 0; ct < 4; ct++) {
        const int n = ct*16 + ln;
        if (n < 56)   // rows 56..63 would spill into the next head's region
          *(unsigned long long*)&hb[VOFFS + n*OS + rt*16 + quad*4] =
              pk4(oacc[rt][ct][0], oacc[rt][ct][1], oacc[rt][ct][2], oacc[rt][ct][3]);
      }
  }

  __syncthreads();   // the ONLY barrier: O slices complete before cross-head reads

  // ---------------- stage D: out^T = Wproj^T · O^T; float4 global stores ----------------
  {
    bf16x8 ob[4][4];  // [ct: n-tile][ks: c-in 32-chunk] ; chunk ks lives in head-ks's region
    #pragma unroll
    for (int ct = 0; ct < 4; ct++)
      #pragma unroll
      for (int ks = 0; ks < 4; ks++)
        ob[ct][ks] = ld8(&lds[ks*HSZ + VOFFS + (ct*16 + ln)*OS + quad*8]);
    float* obp = out + (size_t)b * (NTOK * CDIM);
    #pragma unroll
    for (int rt = 0; rt < 2; rt++) {
      bf16x8 wpa[4];
      #pragma unroll
      for (int ks = 0; ks < 4; ks++)
        wpa[ks] = *(const bf16x8*)&pwp[((((h*2 + rt)*4 + ks)*4 + quad)*16 + ln)*8];
      const int c0 = (h*2 + rt)*16 + quad*4;
      const float4 pb4 = *(const float4*)&proj_b[c0];
      f32x4 pacc[4];
      #pragma unroll
      for (int ct = 0; ct < 4; ct++) { f32x4 bi = {pb4.x, pb4.y, pb4.z, pb4.w}; pacc[ct] = bi; }
      #pragma unroll
      for (int ks = 0; ks < 4; ks++)
        #pragma unroll
        for (int ct = 0; ct < 4; ct++)
          pacc[ct] = __builtin_amdgcn_mfma_f32_16x16x32_bf16(wpa[ks], ob[ct][ks], pacc[ct], 0, 0, 0);
      #pragma unroll
      for (int ct = 0; ct < 4; ct++) {
        const int n = ct*16 + ln;
        if (n < NTOK) {
          float4 v4;
          v4.x = pacc[ct][0]; v4.y = pacc[ct][1]; v4.z = pacc[ct][2]; v4.w = pacc[ct][3];
          *(float4*)(obp + n*CDIM + c0) = v4;
        }
      }
    }
  }
}

extern "C" void kernel_launch(void* const* d_in, const int* in_sizes, int n_in,
                              void* d_out, int out_size, void* d_ws, size_t ws_size,
                              hipStream_t stream) {
  const float* x          = (const float*)d_in[0];
  const float* mask       = (const float*)d_in[1];
  const float* qkv_w      = (const float*)d_in[2];
  const float* qkv_b      = (const float*)d_in[3];
  const float* proj_w     = (const float*)d_in[4];
  const float* proj_b     = (const float*)d_in[5];
  const float* bias_table = (const float*)d_in[6];
  const int*   rel_index  = (const int*)d_in[7];
  float* out = (float*)d_out;

  char* ws = (char*)d_ws;
  float* mask_t         = (float*)ws;
  float* rpb_t          = (float*)(ws + (size_t)MASKT_ELEMS*4);
  unsigned short* pwqk  = (unsigned short*)(ws + (size_t)(MASKT_ELEMS + RPBT_ELEMS)*4);
  unsigned short* pv    = (unsigned short*)(ws + (size_t)(MASKT_ELEMS + RPBT_ELEMS)*4 + (size_t)PWQK_ELEMS*2);
  unsigned short* pwp   = (unsigned short*)(ws + (size_t)(MASKT_ELEMS + RPBT_ELEMS)*4 + (size_t)(PWQK_ELEMS + PV_ELEMS)*2);

  const int total = MASKT_ELEMS + RPBT_ELEMS + PWQK_ELEMS + PV_ELEMS + PWP_ELEMS;
  prep_kernel<<<(total + 255)/256, 256, 0, stream>>>(
      mask, qkv_w, proj_w, bias_table, rel_index, mask_t, rpb_t, pwqk, pv, pwp);
  win_attn_kernel<<<4096, 256, 0, stream>>>(
      x, qkv_b, proj_b, mask_t, rpb_t, pwqk, pv, pwp, out);
}